// Round 6
// baseline (113.111 us; speedup 1.0000x reference)
//
#include <hip/hip_runtime.h>
#include <hip/hip_fp16.h>

// Problem constants
constexpr int B_TOT = 8192;      // batch
constexpr int NM    = 64;        // n_models
constexpr int TT    = 16;        // trees per split
constexpr int LF    = 64;        // maxleaf
constexpr int EM    = 32;        // emb dim
constexpr int XROW  = NM * TT;   // 1024 ints per x row
constexpr int TROWS = TT * LF;   // 1024 rows per model table

// Broadcast quad-lane TQ's int4 to all 4 lanes of each quad via DPP
// (VALU pipe — does NOT load the LDS pipe like __shfl/ds_bpermute would).
template<int TQ>
__device__ __forceinline__ int4 qbcast(int4 v) {
    constexpr int c = TQ * 0x55;          // quad_perm [TQ,TQ,TQ,TQ]
    int4 r;
    r.x = __builtin_amdgcn_mov_dpp(v.x, c, 0xf, 0xf, true);
    r.y = __builtin_amdgcn_mov_dpp(v.y, c, 0xf, 0xf, true);
    r.z = __builtin_amdgcn_mov_dpp(v.z, c, 0xf, 0xf, true);
    r.w = __builtin_amdgcn_mov_dpp(v.w, c, 0xf, 0xf, true);
    return r;
}

__device__ __forceinline__ __half2 H2(unsigned u) { return *(const __half2*)&u; }

// ---------------------------------------------------------------------------
// K1: per-channel batch stats from an LDS-resident f16 table.
// BYTE-IDENTICAL to the proven R0 kernel (108.6us pipeline). R4 re-analysis:
// the b128 layout is already ~bank-optimal (even/odd rows split banks
// 0-15/16-31; E[dwords/bank] ~= 8 = the transfer floor). Do not touch.
// Block: 512 thr owns model m; 64KB f16 table in LDS; 8 phases x 128 b.
// LDS: 64 + 2 KB -> 2 blocks/CU (16 waves). Grid 512 = 64 m x 8 chunks.
// ---------------------------------------------------------------------------
__global__ __launch_bounds__(512, 4) void k_stats_f16(
    const int* __restrict__ x, const float* __restrict__ tbl,
    float* __restrict__ psum, float* __restrict__ psq)
{
    __shared__ uint4 tb[TROWS * 4];      // 64KB f16 table: [row][quad of 8 ch]
    __shared__ float red[2][8][32];      // 2KB reduction scratch

    const int m     = blockIdx.x & 63;
    const int chunk = blockIdx.x >> 6;   // 0..7
    const int tid   = threadIdx.x;
    const int f     = tid & 3;           // channel quad (8 ch) AND t-quad owned
    const int grp   = tid >> 2;          // 0..127 = b within phase
    const int b0    = chunk * 1024;

    // ---- stage + convert table m: f32 128KB -> f16 64KB (4096 uint4) ----
    {
        const float4* __restrict__ src = (const float4*)(tbl + (size_t)m * (TROWS * EM));
#pragma unroll
        for (int i = 0; i < 8; ++i) {
            const int o = tid + i * 512;             // uint4 index 0..4095
            const float4 a = src[o * 2];
            const float4 c = src[o * 2 + 1];
            uint4 p;
            __half2 h0 = __floats2half2_rn(a.x, a.y);
            __half2 h1 = __floats2half2_rn(a.z, a.w);
            __half2 h2 = __floats2half2_rn(c.x, c.y);
            __half2 h3 = __floats2half2_rn(c.z, c.w);
            p.x = *(unsigned*)&h0; p.y = *(unsigned*)&h1;
            p.z = *(unsigned*)&h2; p.w = *(unsigned*)&h3;
            tb[o] = p;
        }
    }

    // ---- prefetch x for phase 0: ONE int4 per lane (t-quad f of b0+grp) ----
    int4 xr = ((const int4*)(x + (size_t)(b0 + grp) * XROW + m * TT))[f];

    float s[8], s2[8];
#pragma unroll
    for (int k = 0; k < 8; ++k) { s[k] = 0.f; s2[k] = 0.f; }

    __syncthreads();                     // tb ready

    for (int p = 0; p < 8; ++p) {
        int4 nxt = xr;
        if (p < 7)                       // next phase's x; hides behind gather
            nxt = ((const int4*)(x + (size_t)(b0 + (p + 1) * 128 + grp) * XROW + m * TT))[f];

        // all 16 tree indices of this quad's b, via quad broadcast
        const int4 q0 = qbcast<0>(xr);
        const int4 q1 = qbcast<1>(xr);
        const int4 q2 = qbcast<2>(xr);
        const int4 q3 = qbcast<3>(xr);

        __half2 h0 = __half2(__half(0.f), __half(0.f));
        __half2 h1 = h0, h2 = h0, h3 = h0;

#define GATH(Q, RB)                                                          \
        {                                                                    \
            const uint4 a0 = tb[((Q).x + RB      ) * 4 + f];                 \
            const uint4 a1 = tb[((Q).y + RB +  64) * 4 + f];                 \
            const uint4 a2 = tb[((Q).z + RB + 128) * 4 + f];                 \
            const uint4 a3 = tb[((Q).w + RB + 192) * 4 + f];                 \
            h0 = __hadd2(h0, __hadd2(__hadd2(H2(a0.x), H2(a1.x)),            \
                                     __hadd2(H2(a2.x), H2(a3.x))));          \
            h1 = __hadd2(h1, __hadd2(__hadd2(H2(a0.y), H2(a1.y)),            \
                                     __hadd2(H2(a2.y), H2(a3.y))));          \
            h2 = __hadd2(h2, __hadd2(__hadd2(H2(a0.z), H2(a1.z)),            \
                                     __hadd2(H2(a2.z), H2(a3.z))));          \
            h3 = __hadd2(h3, __hadd2(__hadd2(H2(a0.w), H2(a1.w)),            \
                                     __hadd2(H2(a2.w), H2(a3.w))));          \
        }
        GATH(q0, 0) GATH(q1, 256) GATH(q2, 512) GATH(q3, 768)
#undef GATH

        const __half2 hv[4] = {h0, h1, h2, h3};
#pragma unroll
        for (int k = 0; k < 4; ++k) {
            const float lo = __low2float(hv[k]);
            const float hi = __high2float(hv[k]);
            s[2*k]   += lo;  s2[2*k]   = fmaf(lo, lo, s2[2*k]);
            s[2*k+1] += hi;  s2[2*k+1] = fmaf(hi, hi, s2[2*k+1]);
        }
        xr = nxt;
    }

    // ---- reduce over grp: butterfly within wave (grp bits = lane 2..5) ----
#pragma unroll
    for (int off = 4; off <= 32; off <<= 1) {
#pragma unroll
        for (int k = 0; k < 8; ++k) {
            s[k]  += __shfl_xor(s[k],  off);
            s2[k] += __shfl_xor(s2[k], off);
        }
    }
    const int wave = tid >> 6;
    if ((tid & 63) < 4) {
#pragma unroll
        for (int k = 0; k < 8; ++k) {
            red[0][wave][f * 8 + k] = s[k];
            red[1][wave][f * 8 + k] = s2[k];
        }
    }
    __syncthreads();
    if (tid < 32) {
        float a = 0.f, a2 = 0.f;
#pragma unroll
        for (int w = 0; w < 8; ++w) { a += red[0][w][tid]; a2 += red[1][w][tid]; }
        psum[(chunk * NM + m) * EM + tid] = a;   // per-(chunk,m) partials:
        psq [(chunk * NM + m) * EM + tid] = a2;  // no atomics, no memset
    }
}

// ---------------------------------------------------------------------------
// K2: sum the 8 chunk-partials, fold BN + projection:
//   a[m,e]=istd*gamma*w; C[m]=bout_b[m]+sum_e (beta-mean*istd*gamma)*w
//   g2[m*1024 + row] = dot(tbl[m,row,:], a[m,:])
// R6 change: g2 is M-MAJOR. (a) K3' stages one model's 4KB strip with a
// single burst; (b) the store is now fully coalesced (old [row][m] layout
// wrote at stride 256B).
// Grid: 256 blocks = 64 m x 4 row-quarters, 256 threads.
// ---------------------------------------------------------------------------
__global__ __launch_bounds__(256) void k_prep(
    const float* __restrict__ tbl,
    const float* __restrict__ gamma, const float* __restrict__ beta,
    const float* __restrict__ bw, const float* __restrict__ bb,
    const float* __restrict__ psum, const float* __restrict__ psq,
    float* __restrict__ Cm, float* __restrict__ g2)
{
    const int m    = blockIdx.x >> 2;
    const int part = blockIdx.x & 3;
    __shared__ float a_s[EM];
    if (threadIdx.x < EM) {
        const int e  = threadIdx.x;
        const int ch = m * EM + e;
        float sum = 0.f, sq = 0.f;
#pragma unroll
        for (int c = 0; c < 8; ++c) {
            sum += psum[(c * NM + m) * EM + e];
            sq  += psq [(c * NM + m) * EM + e];
        }
        const float inv_n = 1.f / (float)B_TOT;
        const float mean = sum * inv_n;
        const float var  = sq * inv_n - mean * mean;
        const float istd = rsqrtf(var + 1e-5f);
        const float g = gamma[ch];
        const float w = bw[ch];
        a_s[e] = istd * g * w;
        float ct = (beta[ch] - mean * istd * g) * w;
#pragma unroll
        for (int off = 16; off > 0; off >>= 1) ct += __shfl_down(ct, off, 32);
        if (e == 0 && part == 0) Cm[m] = bb[m] + ct;
    }
    __syncthreads();

    const float* __restrict__ tblm = tbl + (size_t)m * (TROWS * EM);
    const int row = part * 256 + threadIdx.x;
    const float4* rp = (const float4*)(tblm + row * EM);
    float acc = 0.f;
#pragma unroll
    for (int i = 0; i < 8; ++i) {
        const float4 v = rp[i];
        acc += v.x * a_s[i*4+0] + v.y * a_s[i*4+1]
             + v.z * a_s[i*4+2] + v.w * a_s[i*4+3];
    }
    g2[m * TROWS + row] = acc;           // m-major, coalesced
}

// ---------------------------------------------------------------------------
// K3': out[b,m] = C[m] + sum_t g2[m][t*64 + x[b,m*16+t]]; rowsum by atomic.
// R6 redesign: block = (m, chunk) like K1 -> the per-block gather table is
// ONE model's g2 strip = 4KB LDS (vs R0's 64KB slab x 4 phases x 8 barriers
// x 128MB L2->LDS traffic). x lines (64B = one (b,m) tree-group) are
// disjoint per block -> no fetch amplification. Gather bank = leaf%32,
// random -> ~2-3 lanes/bank, on a 4KB array.
// bid = m*8 + chunk: XCD (bid%8) = chunk, so all 64 m-writers of each
// 64B out-line share one XCD's L2 -> partial stores merge before writeback
// (out is written m-scattered: 16 lanes x 4B at 256B stride).
// Rowsum: out is hipMemsetAsync(0)'d by the harness pre-launch (verified in
// R2 traceback); 64 device-scope atomicAdds per row, f32 order noise ~1e-5.
// Grid: 512 blocks x 512 threads.
// ---------------------------------------------------------------------------
__global__ __launch_bounds__(512) void k_out3(
    const int* __restrict__ x, const float* __restrict__ g2,
    const float* __restrict__ Cm, float* __restrict__ out)
{
    __shared__ float g2s[TROWS];         // 4KB: model m's fused table
    const int m     = blockIdx.x >> 3;
    const int chunk = blockIdx.x & 7;    // = XCD id under round-robin dispatch
    const int tid   = threadIdx.x;
    const int f     = tid & 3;           // t-quad owned (trees f*4..f*4+3)
    const int grp   = tid >> 2;          // 0..127
    const int b0    = chunk * 1024;

    // stage g2 strip for model m: 1024 floats via 512 float2 loads
    ((float2*)g2s)[tid] = ((const float2*)(g2 + m * TROWS))[tid];

    // load this thread's x quads for all 8 sub-phases upfront (32 VGPR);
    // 4 lanes of a quad read one full 64B line (b,m) -> coalesced, disjoint
    int4 xq[8];
#pragma unroll
    for (int p = 0; p < 8; ++p)
        xq[p] = ((const int4*)(x + (size_t)(b0 + p * 128 + grp) * XROW + m * TT))[f];

    const float C = Cm[m];               // block-uniform -> scalar load
    const int base = f * 256;            // row = t*64+leaf = f*256 + j*64 + leaf

    __syncthreads();                     // g2s ready

#pragma unroll
    for (int p = 0; p < 8; ++p) {
        float d = g2s[base       + xq[p].x]
                + g2s[base +  64 + xq[p].y]
                + g2s[base + 128 + xq[p].z]
                + g2s[base + 192 + xq[p].w];
        d += __shfl_xor(d, 1);           // quad-reduce: all 4 lanes get the
        d += __shfl_xor(d, 2);           // sum over 16 trees
        const int b = b0 + p * 128 + grp;
        const float o = d + C;
        if (f == 0) out[B_TOT + (size_t)b * NM + m] = o;   // out tensor (B,M)
        if (f == 1) atomicAdd(&out[b], o);                 // sum_out (B,1)
    }
}

// ---------------------------------------------------------------------------
extern "C" void kernel_launch(void* const* d_in, const int* in_sizes, int n_in,
                              void* d_out, int out_size, void* d_ws, size_t ws_size,
                              hipStream_t stream) {
    const int*   x       = (const int*)d_in[0];
    const float* embed_w = (const float*)d_in[1];
    const float* gamma   = (const float*)d_in[2];
    const float* beta    = (const float*)d_in[3];
    const float* bout_w  = (const float*)d_in[4];
    const float* bout_b  = (const float*)d_in[5];
    float* out = (float*)d_out;

    float* ws   = (float*)d_ws;
    float* psum = ws;                     // 8 chunks x 64 m x 32 e = 16384
    float* psq  = psum + 16384;           // 16384
    float* Cm   = psq + 16384;            // 64
    float* g2   = Cm + 64;                // 65536 (m-major), float2-aligned

    k_stats_f16<<<dim3(512), dim3(512), 0, stream>>>(x, embed_w, psum, psq);
    k_prep<<<dim3(256), dim3(256),  0, stream>>>(embed_w, gamma, beta, bout_w,
                                                 bout_b, psum, psq, Cm, g2);
    k_out3<<<dim3(512), dim3(512),  0, stream>>>(x, g2, Cm, out);
}